// Round 1
// baseline (1681.785 us; speedup 1.0000x reference)
//
#include <hip/hip_runtime.h>

// Problem constants
#define B_  4
#define C_  8
#define T_  512
#define F_  512
#define H_  8
#define DK_ 64
#define M_  (B_*C_*T_)   // 16384 rows

// ---------- bf16 helpers (bit-level, no hip_bf16 dependency) ----------
__device__ __forceinline__ float bf2f(unsigned short s) {
    union { unsigned int u; float f; } c; c.u = ((unsigned int)s) << 16; return c.f;
}
__device__ __forceinline__ unsigned short f2bf(float f) {
    union { float f; unsigned int u; } c; c.f = f;
    unsigned int r = c.u + 0x7fffu + ((c.u >> 16) & 1u);   // RNE
    return (unsigned short)(r >> 16);
}
__device__ __forceinline__ float bflo(unsigned int v){ union{unsigned int u; float f;} c; c.u = v << 16;        return c.f; }
__device__ __forceinline__ float bfhi(unsigned int v){ union{unsigned int u; float f;} c; c.u = v & 0xffff0000u; return c.f; }

__device__ __forceinline__ float4 ld4(const float* p) { return *(const float4*)p; }
__device__ __forceinline__ float4 ld4(const unsigned short* p) {
    ushort4 u = *(const ushort4*)p;
    return make_float4(bf2f(u.x), bf2f(u.y), bf2f(u.z), bf2f(u.w));
}

// ---------------------------------------------------------------------
// Fused complex linear: Yr = Xr Wr^T - Xi Wi^T + (br - bi)
//                       Yi = Xi Wr^T + Xr Wi^T + (br + bi)
// X: (M_, F_) row-major (dtype TIN: float or bf16-as-ushort)
// W: (F_, F_) row-major (fp32), b: (F_) fp32
// PERM_OUT: write Y at ((b*H+h)*T+t)*512 + c*64 + d  (attention layout)
//           else row-major (M_, F_).
// LRELU: apply leaky relu (0.01) to outputs before store.
// Tile: 64x64, BK=16; 256 threads; 4x4 micro-tile, 2 complex accumulators.
// ---------------------------------------------------------------------
template <typename TIN, typename TOUT, bool LRELU, bool PERM_OUT>
__global__ __launch_bounds__(256)
void clinear_kernel(const TIN* __restrict__ Xr, const TIN* __restrict__ Xi,
                    const float* __restrict__ Wr, const float* __restrict__ Wi,
                    const float* __restrict__ br, const float* __restrict__ bi,
                    TOUT* __restrict__ Yr, TOUT* __restrict__ Yi)
{
    // [k][m] / [k][n], pad 64->68 so float4 reads stay aligned & conflict-light
    __shared__ __align__(16) float sXr[16][68];
    __shared__ __align__(16) float sXi[16][68];
    __shared__ __align__(16) float sWr[16][68];
    __shared__ __align__(16) float sWi[16][68];

    const int tid  = threadIdx.x;
    const int m0   = blockIdx.x << 6;
    const int n0   = blockIdx.y << 6;
    const int tm   = tid >> 4;          // 0..15
    const int tn   = tid & 15;          // 0..15
    const int lrow = tid >> 2;          // 0..63 loader row
    const int lcol = (tid & 3) << 2;    // 0,4,8,12 loader col

    float accr[4][4] = {}; float acci[4][4] = {};

    const size_t xrow = (size_t)(m0 + lrow) * F_;
    const size_t wrow = (size_t)(n0 + lrow) * F_;

    for (int k0 = 0; k0 < F_; k0 += 16) {
        const float4 xr4 = ld4(Xr + xrow + k0 + lcol);
        const float4 xi4 = ld4(Xi + xrow + k0 + lcol);
        const float4 wr4 = ld4(Wr + wrow + k0 + lcol);
        const float4 wi4 = ld4(Wi + wrow + k0 + lcol);
        __syncthreads();
        sXr[lcol+0][lrow]=xr4.x; sXr[lcol+1][lrow]=xr4.y; sXr[lcol+2][lrow]=xr4.z; sXr[lcol+3][lrow]=xr4.w;
        sXi[lcol+0][lrow]=xi4.x; sXi[lcol+1][lrow]=xi4.y; sXi[lcol+2][lrow]=xi4.z; sXi[lcol+3][lrow]=xi4.w;
        sWr[lcol+0][lrow]=wr4.x; sWr[lcol+1][lrow]=wr4.y; sWr[lcol+2][lrow]=wr4.z; sWr[lcol+3][lrow]=wr4.w;
        sWi[lcol+0][lrow]=wi4.x; sWi[lcol+1][lrow]=wi4.y; sWi[lcol+2][lrow]=wi4.z; sWi[lcol+3][lrow]=wi4.w;
        __syncthreads();
        #pragma unroll
        for (int kk = 0; kk < 16; ++kk) {
            const float4 a4 = *(const float4*)&sXr[kk][tm<<2];
            const float4 c4 = *(const float4*)&sXi[kk][tm<<2];
            const float4 b4 = *(const float4*)&sWr[kk][tn<<2];
            const float4 d4 = *(const float4*)&sWi[kk][tn<<2];
            const float ar[4]  = {a4.x,a4.y,a4.z,a4.w};
            const float ai[4]  = {c4.x,c4.y,c4.z,c4.w};
            const float wrv[4] = {b4.x,b4.y,b4.z,b4.w};
            const float wiv[4] = {d4.x,d4.y,d4.z,d4.w};
            #pragma unroll
            for (int i = 0; i < 4; ++i) {
                #pragma unroll
                for (int j = 0; j < 4; ++j) {
                    accr[i][j] = fmaf(ar[i],  wrv[j], accr[i][j]);
                    accr[i][j] = fmaf(-ai[i], wiv[j], accr[i][j]);
                    acci[i][j] = fmaf(ai[i],  wrv[j], acci[i][j]);
                    acci[i][j] = fmaf(ar[i],  wiv[j], acci[i][j]);
                }
            }
        }
    }

    const int nb = n0 + (tn << 2);
    float b_r[4], b_i[4];
    #pragma unroll
    for (int j = 0; j < 4; ++j) { b_r[j] = br[nb+j]; b_i[j] = bi[nb+j]; }

    #pragma unroll
    for (int i = 0; i < 4; ++i) {
        const int m = m0 + (tm << 2) + i;
        size_t base;
        if constexpr (PERM_OUT) {
            // m = (b*C + c)*T + t ; n-range of this block is exactly one head
            const int bb = m >> 12;        // / (C*T) = /4096
            const int cc = (m >> 9) & 7;
            const int tt = m & 511;
            const int hh = n0 >> 6;
            base = ((size_t)(((bb << 3) + hh) * T_ + tt) << 9) + (cc << 6) + (nb & 63);
        } else {
            base = (size_t)m * F_ + nb;
        }
        #pragma unroll
        for (int j = 0; j < 4; ++j) {
            float vr_ = accr[i][j] + b_r[j] - b_i[j];
            float vi_ = acci[i][j] + b_r[j] + b_i[j];
            if constexpr (LRELU) {
                vr_ = vr_ >= 0.f ? vr_ : 0.01f * vr_;
                vi_ = vi_ >= 0.f ? vi_ : 0.01f * vi_;
            }
            if constexpr (sizeof(TOUT) == 2) {
                Yr[base + j] = f2bf(vr_);
                Yi[base + j] = f2bf(vi_);
            } else {
                Yr[base + j] = vr_;
                Yi[base + j] = vi_;
            }
        }
    }
}

// ---------------------------------------------------------------------
// Attention: per (b,h,t) chunk w = (b*H+h)*T + t, each matrix stored as
// 512 contiguous bf16 (c*64+d) at offset w*512.
//   sr = (qr·kr^T + qi·ki^T)*0.125 ; si = (qr·ki^T - qi·kr^T)*0.125
//   xr = sr vr - si vi ; xi = si vr + sr vi   (sums over channel e)
// lrelu applied to v was done in K1; lrelu applied here to merged output.
// One wave per (b,h,t); 4 waves (256 thr) per block.
// ---------------------------------------------------------------------
__global__ __launch_bounds__(256)
void attn_kernel(const unsigned short* __restrict__ qr, const unsigned short* __restrict__ qi,
                 const unsigned short* __restrict__ kr, const unsigned short* __restrict__ ki,
                 const unsigned short* __restrict__ vr, const unsigned short* __restrict__ vi,
                 unsigned short* __restrict__ xr, unsigned short* __restrict__ xi)
{
    constexpr int RS = 68;        // padded row stride (floats)
    constexpr int MS = 8 * RS;    // per matrix: 544 floats
    __shared__ float L[4][6 * MS];     // 52224 B
    __shared__ float S[4][128];        // sr(64) + si(64) per wave

    const int wave = threadIdx.x >> 6;
    const int lane = threadIdx.x & 63;
    const int w    = (blockIdx.x << 2) + wave;   // (b*H+h)*T + t
    const int cl   = lane >> 3;                  // row / c-index 0..7
    const int dl   = lane & 7;                   // 0..7
    const int d0   = dl << 3;                    // 0,8,..,56

    float* Lw = L[wave];
    const unsigned short* srcs[6] = {qr, qi, kr, ki, vr, vi};
    const size_t gbase = ((size_t)w << 9) + (lane << 3);
    #pragma unroll
    for (int m2 = 0; m2 < 6; ++m2) {
        const uint4 u = *(const uint4*)(srcs[m2] + gbase);
        float* dst = Lw + m2 * MS + cl * RS + d0;
        dst[0]=bflo(u.x); dst[1]=bfhi(u.x);
        dst[2]=bflo(u.y); dst[3]=bfhi(u.y);
        dst[4]=bflo(u.z); dst[5]=bfhi(u.z);
        dst[6]=bflo(u.w); dst[7]=bfhi(u.w);
    }
    __syncthreads();

    // ---- scores: lane -> (c=cl, e=dl) ----
    {
        const float* Qr = Lw + 0*MS + cl*RS;
        const float* Qi = Lw + 1*MS + cl*RS;
        const float* Kr = Lw + 2*MS + dl*RS;
        const float* Ki = Lw + 3*MS + dl*RS;
        float srr=0.f, sii=0.f, sri=0.f, sir=0.f;
        #pragma unroll 8
        for (int d = 0; d < 64; ++d) {
            srr = fmaf(Qr[d], Kr[d], srr);
            sii = fmaf(Qi[d], Ki[d], sii);
            sri = fmaf(Qr[d], Ki[d], sri);
            sir = fmaf(Qi[d], Kr[d], sir);
        }
        S[wave][lane]      = (srr + sii) * 0.125f;   // sr[c][e]
        S[wave][64 + lane] = (sri - sir) * 0.125f;   // si[c][e]
    }
    __syncthreads();

    // ---- output: lane -> (c=cl, d in [d0, d0+8)) ----
    const float* Vr = Lw + 4*MS;
    const float* Vi = Lw + 5*MS;
    const float* Sr = S[wave];
    const float* Si = S[wave] + 64;
    float outr[8] = {}, outi[8] = {};
    #pragma unroll
    for (int e = 0; e < 8; ++e) {
        const float sre = Sr[(cl<<3) + e];
        const float sie = Si[(cl<<3) + e];
        const float* vre = Vr + e*RS + d0;
        const float* vie = Vi + e*RS + d0;
        #pragma unroll
        for (int j = 0; j < 8; ++j) {
            outr[j] = fmaf(sre,  vre[j], outr[j]);
            outr[j] = fmaf(-sie, vie[j], outr[j]);
            outi[j] = fmaf(sie,  vre[j], outi[j]);
            outi[j] = fmaf(sre,  vie[j], outi[j]);
        }
    }

    // write merged (B,C,T,F) bf16 with lrelu
    const int tt = w & 511, hh = (w >> 9) & 7, bb = w >> 12;
    const size_t obase = ((size_t)(((bb << 3) + cl) * T_ + tt) << 9) + (hh << 6) + d0;
    unsigned int pr[4], pi[4];
    #pragma unroll
    for (int jj = 0; jj < 4; ++jj) {
        float r0 = outr[2*jj], r1 = outr[2*jj+1];
        float i0 = outi[2*jj], i1 = outi[2*jj+1];
        r0 = r0 >= 0.f ? r0 : 0.01f*r0;  r1 = r1 >= 0.f ? r1 : 0.01f*r1;
        i0 = i0 >= 0.f ? i0 : 0.01f*i0;  i1 = i1 >= 0.f ? i1 : 0.01f*i1;
        pr[jj] = (unsigned int)f2bf(r0) | ((unsigned int)f2bf(r1) << 16);
        pi[jj] = (unsigned int)f2bf(i0) | ((unsigned int)f2bf(i1) << 16);
    }
    *(uint4*)(xr + obase) = make_uint4(pr[0], pr[1], pr[2], pr[3]);
    *(uint4*)(xi + obase) = make_uint4(pi[0], pi[1], pi[2], pi[3]);
}

// ---------------------------------------------------------------------
extern "C" void kernel_launch(void* const* d_in, const int* in_sizes, int n_in,
                              void* d_out, int out_size, void* d_ws, size_t ws_size,
                              hipStream_t stream)
{
    (void)in_sizes; (void)n_in; (void)out_size; (void)ws_size;
    const float* query_r = (const float*)d_in[0];
    const float* query_i = (const float*)d_in[1];
    const float* key_r   = (const float*)d_in[2];
    const float* key_i   = (const float*)d_in[3];
    const float* value_r = (const float*)d_in[4];
    const float* value_i = (const float*)d_in[5];
    const float* Wq_r = (const float*)d_in[6];
    const float* bq_r = (const float*)d_in[7];
    const float* Wq_i = (const float*)d_in[8];
    const float* bq_i = (const float*)d_in[9];
    const float* Wk_r = (const float*)d_in[10];
    const float* bk_r = (const float*)d_in[11];
    const float* Wk_i = (const float*)d_in[12];
    const float* bk_i = (const float*)d_in[13];
    const float* Wv_r = (const float*)d_in[14];
    const float* bv_r = (const float*)d_in[15];
    const float* Wv_i = (const float*)d_in[16];
    const float* bv_i = (const float*)d_in[17];
    const float* Wo_r = (const float*)d_in[18];
    const float* bo_r = (const float*)d_in[19];
    const float* Wo_i = (const float*)d_in[20];
    const float* bo_i = (const float*)d_in[21];

    const size_t SZ = (size_t)M_ * F_;        // 8,388,608 elements
    unsigned short* ws = (unsigned short*)d_ws;
    unsigned short* qr = ws + 0*SZ;
    unsigned short* qi = ws + 1*SZ;
    unsigned short* kr = ws + 2*SZ;
    unsigned short* ki = ws + 3*SZ;
    unsigned short* vr = ws + 4*SZ;
    unsigned short* vi = ws + 5*SZ;
    unsigned short* xr = ws + 6*SZ;
    unsigned short* xi = ws + 7*SZ;

    dim3 grid(M_/64, F_/64);
    dim3 blk(256);

    clinear_kernel<float, unsigned short, false, true><<<grid, blk, 0, stream>>>(
        query_r, query_i, Wq_r, Wq_i, bq_r, bq_i, qr, qi);
    clinear_kernel<float, unsigned short, false, true><<<grid, blk, 0, stream>>>(
        key_r, key_i, Wk_r, Wk_i, bk_r, bk_i, kr, ki);
    clinear_kernel<float, unsigned short, true, true><<<grid, blk, 0, stream>>>(
        value_r, value_i, Wv_r, Wv_i, bv_r, bv_i, vr, vi);

    attn_kernel<<<dim3((B_*H_*T_)/4), blk, 0, stream>>>(qr, qi, kr, ki, vr, vi, xr, xi);

    float* out_r = (float*)d_out;
    float* out_i = out_r + SZ;
    clinear_kernel<unsigned short, float, false, false><<<grid, blk, 0, stream>>>(
        xr, xi, Wo_r, Wo_i, bo_r, bo_i, out_r, out_i);
}

// Round 2
// 517.832 us; speedup vs baseline: 3.2477x; 3.2477x over previous
//
#include <hip/hip_runtime.h>

// Problem constants
#define B_  4
#define C_  8
#define T_  512
#define F_  512
#define H_  8
#define M_  (B_*C_*T_)   // 16384 rows

typedef unsigned short u16;
typedef unsigned int   u32;
typedef __bf16 bf16x8 __attribute__((ext_vector_type(8)));
typedef float  f32x4  __attribute__((ext_vector_type(4)));

// ---------- bf16 helpers ----------
__device__ __forceinline__ float bf2f(u16 s) {
    union { u32 u; float f; } c; c.u = ((u32)s) << 16; return c.f;
}
__device__ __forceinline__ u16 f2bf(float f) {
    union { float f; u32 u; } c; c.f = f;
    u32 r = c.u + 0x7fffu + ((c.u >> 16) & 1u);   // RNE
    return (u16)(r >> 16);
}
__device__ __forceinline__ float bflo(u32 v){ union{u32 u; float f;} c; c.u = v << 16;        return c.f; }
__device__ __forceinline__ float bfhi(u32 v){ union{u32 u; float f;} c; c.u = v & 0xffff0000u; return c.f; }

// async global->LDS, 16 B per lane. lds must be the wave-uniform base.
__device__ __forceinline__ void async16(u16* lds, const u16* g) {
    __builtin_amdgcn_global_load_lds(
        (const __attribute__((address_space(1))) u32*)g,
        (__attribute__((address_space(3))) u32*)lds,
        16, 0, 0);
}

// ---------------------------------------------------------------------
// K0: fp32 -> bf16 convert, 6 tensors of M_*F_ elements. 8 elems/thread.
// ---------------------------------------------------------------------
struct ConvArgs { const float* src[6]; u16* dst[6]; };

__global__ __launch_bounds__(256)
void convert6_kernel(ConvArgs a)
{
    const int t = blockIdx.x * 256 + threadIdx.x;
    const float4* s = (const float4*)a.src[blockIdx.y] + (size_t)t * 2;
    const float4 x = s[0], y = s[1];
    uint4 o;
    o.x = (u32)f2bf(x.x) | ((u32)f2bf(x.y) << 16);
    o.y = (u32)f2bf(x.z) | ((u32)f2bf(x.w) << 16);
    o.z = (u32)f2bf(y.x) | ((u32)f2bf(y.y) << 16);
    o.w = (u32)f2bf(y.z) | ((u32)f2bf(y.w) << 16);
    *(uint4*)(a.dst[blockIdx.y] + (size_t)t * 8) = o;
}

// ---------------------------------------------------------------------
// Kp: build WbigBT (1024x1024 bf16, [n][k]) and biasBig (1024 fp32) per stage.
//  n<512: k<512 -> Wr[n][k]     ; k>=512 -> -Wi[n][k-512]
//  n>=512:k<512 -> Wi[n-512][k] ; k>=512 ->  Wr[n-512][k-512]
//  bias: n<512 -> br-bi ; n>=512 -> br+bi
// ---------------------------------------------------------------------
struct PrepArgs { const float* wr[4]; const float* wi[4]; const float* br[4]; const float* bi[4]; };

__global__ __launch_bounds__(256)
void prep_weights_kernel(PrepArgs a, u16* __restrict__ wbig, float* __restrict__ bbig)
{
    const int s   = blockIdx.y;
    const int idx = blockIdx.x * 256 + threadIdx.x;   // 0 .. 262143
    const int n   = idx >> 8;                         // 0..1023
    const int k0  = (idx & 255) << 2;                 // 0..1020
    const int nn = n & 511, kk = k0 & 511;
    const float* src; float sgn = 1.0f;
    if (n < 512) { if (k0 < 512) src = a.wr[s]; else { src = a.wi[s]; sgn = -1.0f; } }
    else         { if (k0 < 512) src = a.wi[s]; else   src = a.wr[s]; }
    const float4 v = *(const float4*)(src + (size_t)nn * 512 + kk);
    ushort4 q;
    q.x = f2bf(sgn * v.x); q.y = f2bf(sgn * v.y);
    q.z = f2bf(sgn * v.z); q.w = f2bf(sgn * v.w);
    *(ushort4*)(wbig + (size_t)s * 1048576 + (size_t)n * 1024 + k0) = q;

    if (blockIdx.x < 4) {
        const int bidx = blockIdx.x * 256 + threadIdx.x;   // 0..1023
        const float brv = a.br[s][bidx & 511];
        const float biv = a.bi[s][bidx & 511];
        bbig[s * 1024 + bidx] = (bidx < 512) ? (brv - biv) : (brv + biv);
    }
}

// ---------------------------------------------------------------------
// MFMA complex-linear as packed real GEMM:
//   Y[m,n] = sum_k Xcat[m,k] * WbigBT[n,k] + biasBig[n]
//   Xcat: k<512 from Ar (row-major M x 512 bf16), k>=512 from Ai.
//   cols n<512 -> Yr, n>=512 -> Yi.
// Tile 128x128, BK=32, 256 threads (4 waves, each 64x64 = 4x4 MFMA tiles).
// m97 structure: global_load_lds width 16, 2-barrier K-loop.
// ---------------------------------------------------------------------
template <bool PERM_OUT, bool LRELU, bool OUT_F32>
__global__ __launch_bounds__(256)
void mfma_clinear_kernel(const u16* __restrict__ Ar, const u16* __restrict__ Ai,
                         const u16* __restrict__ Wbt, const float* __restrict__ bias,
                         void* __restrict__ Yr_, void* __restrict__ Yi_)
{
    __shared__ __align__(16) u16 sA[128 * 32];
    __shared__ __align__(16) u16 sB[128 * 32];

    const int tid  = threadIdx.x;
    const int wave = tid >> 6;
    const int lane = tid & 63;
    const int m0   = blockIdx.x << 7;
    const int n0   = blockIdx.y << 7;
    const int mw   = (wave >> 1) << 6;   // 0 / 64
    const int nw   = (wave & 1) << 6;    // 0 / 64

    // staging addresses: thread t (issue i) covers tile element (i*64 + t/4, (t&3)*8)
    const int srow = tid >> 2;           // 0..63
    const int sk   = (tid & 3) << 3;     // 0,8,16,24
    const size_t arow0 = (size_t)(m0 + srow) * 512;
    const size_t arow1 = (size_t)(m0 + 64 + srow) * 512;
    const size_t brow0 = (size_t)(n0 + srow) * 1024;
    const size_t brow1 = (size_t)(n0 + 64 + srow) * 1024;

    // wave-uniform LDS bases (elements): issue i, wave w -> (i*4+w)*512
    u16* ldsA0 = &sA[wave * 512];
    u16* ldsA1 = &sA[2048 + wave * 512];
    u16* ldsB0 = &sB[wave * 512];
    u16* ldsB1 = &sB[2048 + wave * 512];

    f32x4 acc[4][4] = {};

    const int fr = lane & 15;            // fragment row (m or n)
    const int fq = (lane >> 4) << 3;     // fragment k offset

    for (int k0 = 0; k0 < 1024; k0 += 32) {
        const u16* As = (k0 < 512) ? Ar : Ai;
        const int  ak = (k0 & 511) + sk;
        __syncthreads();
        async16(ldsA0, As + arow0 + ak);
        async16(ldsA1, As + arow1 + ak);
        async16(ldsB0, Wbt + brow0 + k0 + sk);
        async16(ldsB1, Wbt + brow1 + k0 + sk);
        __syncthreads();

        bf16x8 af[4], bfr[4];
        #pragma unroll
        for (int i = 0; i < 4; ++i)
            af[i] = *(const bf16x8*)&sA[(mw + i * 16 + fr) * 32 + fq];
        #pragma unroll
        for (int j = 0; j < 4; ++j)
            bfr[j] = *(const bf16x8*)&sB[(nw + j * 16 + fr) * 32 + fq];

        #pragma unroll
        for (int i = 0; i < 4; ++i)
            #pragma unroll
            for (int j = 0; j < 4; ++j)
                acc[i][j] = __builtin_amdgcn_mfma_f32_16x16x32_bf16(af[i], bfr[j], acc[i][j], 0, 0, 0);
    }

    // epilogue: C[row=(lane>>4)*4+reg][col=lane&15]
    const int col_l = lane & 15;
    const int row_l = (lane >> 4) << 2;
    #pragma unroll
    for (int j = 0; j < 4; ++j) {
        const int ncol = n0 + nw + j * 16 + col_l;       // 0..1023
        const float bv = bias[ncol];
        const int part = ncol >> 9;                      // 0 -> r, 1 -> i
        const int nc   = ncol & 511;
        #pragma unroll
        for (int i = 0; i < 4; ++i) {
            const int mbase = m0 + mw + i * 16 + row_l;
            #pragma unroll
            for (int r = 0; r < 4; ++r) {
                const int m = mbase + r;
                float v = acc[i][j][r] + bv;
                if constexpr (LRELU) v = v >= 0.f ? v : 0.01f * v;
                size_t addr;
                if constexpr (PERM_OUT) {
                    const int bb = m >> 12, cc = (m >> 9) & 7, tt = m & 511;
                    const int hh = nc >> 6, dd = nc & 63;
                    addr = ((size_t)(((bb << 3) + hh) * T_ + tt) << 9) + (cc << 6) + dd;
                } else {
                    addr = (size_t)m * 512 + nc;
                }
                if constexpr (OUT_F32) {
                    float* Y = part ? (float*)Yi_ : (float*)Yr_;
                    Y[addr] = v;
                } else {
                    u16* Y = part ? (u16*)Yi_ : (u16*)Yr_;
                    Y[addr] = f2bf(v);
                }
            }
        }
    }
}

// ---------------------------------------------------------------------
// Attention: per (b,h,t) chunk w = (b*H+h)*T + t, matrices stored as
// 512 contiguous bf16 (c*64+d) at offset w*512.
// ---------------------------------------------------------------------
__global__ __launch_bounds__(256)
void attn_kernel(const u16* __restrict__ qr, const u16* __restrict__ qi,
                 const u16* __restrict__ kr, const u16* __restrict__ ki,
                 const u16* __restrict__ vr, const u16* __restrict__ vi,
                 u16* __restrict__ xr, u16* __restrict__ xi)
{
    constexpr int RS = 68;        // padded row stride (floats)
    constexpr int MS = 8 * RS;    // per matrix: 544 floats
    __shared__ float L[4][6 * MS];     // 52224 B
    __shared__ float S[4][128];        // sr(64) + si(64) per wave

    const int wave = threadIdx.x >> 6;
    const int lane = threadIdx.x & 63;
    const int w    = (blockIdx.x << 2) + wave;   // (b*H+h)*T + t
    const int cl   = lane >> 3;                  // c-index 0..7
    const int dl   = lane & 7;                   // 0..7
    const int d0   = dl << 3;                    // 0,8,..,56

    float* Lw = L[wave];
    const u16* srcs[6] = {qr, qi, kr, ki, vr, vi};
    const size_t gbase = ((size_t)w << 9) + (lane << 3);
    #pragma unroll
    for (int m2 = 0; m2 < 6; ++m2) {
        const uint4 u = *(const uint4*)(srcs[m2] + gbase);
        float* dst = Lw + m2 * MS + cl * RS + d0;
        dst[0]=bflo(u.x); dst[1]=bfhi(u.x);
        dst[2]=bflo(u.y); dst[3]=bfhi(u.y);
        dst[4]=bflo(u.z); dst[5]=bfhi(u.z);
        dst[6]=bflo(u.w); dst[7]=bfhi(u.w);
    }
    __syncthreads();

    { // scores: lane -> (c=cl, e=dl)
        const float* Qr = Lw + 0*MS + cl*RS;
        const float* Qi = Lw + 1*MS + cl*RS;
        const float* Kr = Lw + 2*MS + dl*RS;
        const float* Ki = Lw + 3*MS + dl*RS;
        float srr=0.f, sii=0.f, sri=0.f, sir=0.f;
        #pragma unroll 8
        for (int d = 0; d < 64; ++d) {
            srr = fmaf(Qr[d], Kr[d], srr);
            sii = fmaf(Qi[d], Ki[d], sii);
            sri = fmaf(Qr[d], Ki[d], sri);
            sir = fmaf(Qi[d], Kr[d], sir);
        }
        S[wave][lane]      = (srr + sii) * 0.125f;   // sr[c][e]
        S[wave][64 + lane] = (sri - sir) * 0.125f;   // si[c][e]
    }
    __syncthreads();

    const float* Vr = Lw + 4*MS;
    const float* Vi = Lw + 5*MS;
    const float* Sr = S[wave];
    const float* Si = S[wave] + 64;
    float outr[8] = {}, outi[8] = {};
    #pragma unroll
    for (int e = 0; e < 8; ++e) {
        const float sre = Sr[(cl<<3) + e];
        const float sie = Si[(cl<<3) + e];
        const float* vre = Vr + e*RS + d0;
        const float* vie = Vi + e*RS + d0;
        #pragma unroll
        for (int j = 0; j < 8; ++j) {
            outr[j] = fmaf(sre,  vre[j], outr[j]);
            outr[j] = fmaf(-sie, vie[j], outr[j]);
            outi[j] = fmaf(sie,  vre[j], outi[j]);
            outi[j] = fmaf(sre,  vie[j], outi[j]);
        }
    }

    // write merged (B,C,T,F) bf16 with lrelu
    const int tt = w & 511, hh = (w >> 9) & 7, bb = w >> 12;
    const size_t obase = ((size_t)(((bb << 3) + cl) * T_ + tt) << 9) + (hh << 6) + d0;
    u32 pr[4], pi[4];
    #pragma unroll
    for (int jj = 0; jj < 4; ++jj) {
        float r0 = outr[2*jj], r1 = outr[2*jj+1];
        float i0 = outi[2*jj], i1 = outi[2*jj+1];
        r0 = r0 >= 0.f ? r0 : 0.01f*r0;  r1 = r1 >= 0.f ? r1 : 0.01f*r1;
        i0 = i0 >= 0.f ? i0 : 0.01f*i0;  i1 = i1 >= 0.f ? i1 : 0.01f*i1;
        pr[jj] = (u32)f2bf(r0) | ((u32)f2bf(r1) << 16);
        pi[jj] = (u32)f2bf(i0) | ((u32)f2bf(i1) << 16);
    }
    *(uint4*)(xr + obase) = make_uint4(pr[0], pr[1], pr[2], pr[3]);
    *(uint4*)(xi + obase) = make_uint4(pi[0], pi[1], pi[2], pi[3]);
}

// ---------------------------------------------------------------------
extern "C" void kernel_launch(void* const* d_in, const int* in_sizes, int n_in,
                              void* d_out, int out_size, void* d_ws, size_t ws_size,
                              hipStream_t stream)
{
    (void)in_sizes; (void)n_in; (void)out_size; (void)ws_size;
    const float* act[6];
    for (int i = 0; i < 6; ++i) act[i] = (const float*)d_in[i];

    PrepArgs pa;
    // order in d_in: Wq_r,bq_r,Wq_i,bq_i, Wk_r,bk_r,Wk_i,bk_i, Wv_r,bv_r,Wv_i,bv_i, Wo_r,bo_r,Wo_i,bo_i
    for (int s = 0; s < 4; ++s) {
        pa.wr[s] = (const float*)d_in[6 + s*4 + 0];
        pa.br[s] = (const float*)d_in[6 + s*4 + 1];
        pa.wi[s] = (const float*)d_in[6 + s*4 + 2];
        pa.bi[s] = (const float*)d_in[6 + s*4 + 3];
    }

    const size_t SZ = (size_t)M_ * F_;        // 8,388,608 elements
    u16* ws = (u16*)d_ws;
    u16* a0 = ws + 0*SZ;  u16* a1 = ws + 1*SZ;   // query bf16 -> later k outputs
    u16* a2 = ws + 2*SZ;  u16* a3 = ws + 3*SZ;   // key bf16   -> later v outputs
    u16* a4 = ws + 4*SZ;  u16* a5 = ws + 5*SZ;   // value bf16 -> later attn outputs
    u16* q0 = ws + 6*SZ;  u16* q1 = ws + 7*SZ;   // q outputs
    u16*   wbig = ws + 8*SZ;                      // 4 x 1M bf16
    float* bbig = (float*)(wbig + 4u*1024*1024);  // 4 x 1024 fp32

    ConvArgs ca;
    ca.src[0]=act[0]; ca.src[1]=act[1]; ca.src[2]=act[2];
    ca.src[3]=act[3]; ca.src[4]=act[4]; ca.src[5]=act[5];
    ca.dst[0]=a0; ca.dst[1]=a1; ca.dst[2]=a2; ca.dst[3]=a3; ca.dst[4]=a4; ca.dst[5]=a5;

    convert6_kernel<<<dim3(4096, 6), 256, 0, stream>>>(ca);
    prep_weights_kernel<<<dim3(1024, 4), 256, 0, stream>>>(pa, wbig, bbig);

    dim3 ggrid(M_/128, 1024/128);
    // q stage
    mfma_clinear_kernel<true,  false, false><<<ggrid, 256, 0, stream>>>(
        a0, a1, wbig + 0u*1048576, bbig + 0*1024, q0, q1);
    // k stage (writes into a0/a1, already consumed)
    mfma_clinear_kernel<true,  false, false><<<ggrid, 256, 0, stream>>>(
        a2, a3, wbig + 1u*1048576, bbig + 1*1024, a0, a1);
    // v stage with leaky-relu (writes into a2/a3)
    mfma_clinear_kernel<true,  true,  false><<<ggrid, 256, 0, stream>>>(
        a4, a5, wbig + 2u*1048576, bbig + 2*1024, a2, a3);

    // attention: q=q0/q1, k=a0/a1, v=a2/a3 -> merged xr=a4, xi=a5
    attn_kernel<<<dim3((B_*H_*T_)/4), 256, 0, stream>>>(q0, q1, a0, a1, a2, a3, a4, a5);

    // output stage: fp32 out, no perm, no lrelu
    float* out_r = (float*)d_out;
    mfma_clinear_kernel<false, false, true><<<ggrid, 256, 0, stream>>>(
        a4, a5, wbig + 3u*1048576, bbig + 3*1024, out_r, out_r + SZ);
}

// Round 3
// 476.769 us; speedup vs baseline: 3.5275x; 1.0861x over previous
//
#include <hip/hip_runtime.h>

// Problem constants
#define B_  4
#define C_  8
#define T_  512
#define F_  512
#define H_  8
#define M_  (B_*C_*T_)   // 16384 rows

typedef unsigned short u16;
typedef unsigned int   u32;
typedef __bf16 bf16x8 __attribute__((ext_vector_type(8)));
typedef float  f32x4  __attribute__((ext_vector_type(4)));

// ---------- bf16 helpers ----------
__device__ __forceinline__ float bf2f(u16 s) {
    union { u32 u; float f; } c; c.u = ((u32)s) << 16; return c.f;
}
__device__ __forceinline__ u16 f2bf(float f) {
    union { float f; u32 u; } c; c.f = f;
    u32 r = c.u + 0x7fffu + ((c.u >> 16) & 1u);   // RNE
    return (u16)(r >> 16);
}
__device__ __forceinline__ float bflo(u32 v){ union{u32 u; float f;} c; c.u = v << 16;        return c.f; }
__device__ __forceinline__ float bfhi(u32 v){ union{u32 u; float f;} c; c.u = v & 0xffff0000u; return c.f; }

// async global->LDS, 16 B per lane. lds must be the wave-uniform base.
__device__ __forceinline__ void async16(u16* lds, const u16* g) {
    __builtin_amdgcn_global_load_lds(
        (const __attribute__((address_space(1))) u32*)g,
        (__attribute__((address_space(3))) u32*)lds,
        16, 0, 0);
}

// ---------------------------------------------------------------------
// K0: fp32 -> bf16 convert, 6 tensors of M_*F_ elements. 32 elems/thread.
// ---------------------------------------------------------------------
struct ConvArgs { const float* src[6]; u16* dst[6]; };

__global__ __launch_bounds__(256)
void convert6_kernel(ConvArgs a)
{
    const int t = blockIdx.x * 256 + threadIdx.x;          // 0..262143
    const float4* s = (const float4*)a.src[blockIdx.y] + (size_t)t * 8;
    uint4*       d = (uint4*)a.dst[blockIdx.y] + (size_t)t * 4;
    float4 x[8];
    #pragma unroll
    for (int i = 0; i < 8; ++i) x[i] = s[i];
    #pragma unroll
    for (int i = 0; i < 4; ++i) {
        uint4 o;
        o.x = (u32)f2bf(x[2*i].x)   | ((u32)f2bf(x[2*i].y)   << 16);
        o.y = (u32)f2bf(x[2*i].z)   | ((u32)f2bf(x[2*i].w)   << 16);
        o.z = (u32)f2bf(x[2*i+1].x) | ((u32)f2bf(x[2*i+1].y) << 16);
        o.w = (u32)f2bf(x[2*i+1].z) | ((u32)f2bf(x[2*i+1].w) << 16);
        d[i] = o;
    }
}

// ---------------------------------------------------------------------
// Kp: build WbigBT (1024x1024 bf16, [n][k]) and biasBig (1024 fp32) per stage.
// ---------------------------------------------------------------------
struct PrepArgs { const float* wr[4]; const float* wi[4]; const float* br[4]; const float* bi[4]; };

__global__ __launch_bounds__(256)
void prep_weights_kernel(PrepArgs a, u16* __restrict__ wbig, float* __restrict__ bbig)
{
    const int s   = blockIdx.y;
    const int idx = blockIdx.x * 256 + threadIdx.x;   // 0 .. 262143
    const int n   = idx >> 8;                         // 0..1023
    const int k0  = (idx & 255) << 2;                 // 0..1020
    const int nn = n & 511, kk = k0 & 511;
    const float* src; float sgn = 1.0f;
    if (n < 512) { if (k0 < 512) src = a.wr[s]; else { src = a.wi[s]; sgn = -1.0f; } }
    else         { if (k0 < 512) src = a.wi[s]; else   src = a.wr[s]; }
    const float4 v = *(const float4*)(src + (size_t)nn * 512 + kk);
    ushort4 q;
    q.x = f2bf(sgn * v.x); q.y = f2bf(sgn * v.y);
    q.z = f2bf(sgn * v.z); q.w = f2bf(sgn * v.w);
    *(ushort4*)(wbig + (size_t)s * 1048576 + (size_t)n * 1024 + k0) = q;

    if (blockIdx.x < 4) {
        const int bidx = blockIdx.x * 256 + threadIdx.x;   // 0..1023
        const float brv = a.br[s][bidx & 511];
        const float biv = a.bi[s][bidx & 511];
        bbig[s * 1024 + bidx] = (bidx < 512) ? (brv - biv) : (brv + biv);
    }
}

// ---------------------------------------------------------------------
// MFMA complex-linear as packed real GEMM (m97 structure):
//   Y[m,n] = sum_k Xcat[m,k] * WbigBT[n,k] + biasBig[n]
// Tile 128x128, BK=32, 256 threads (4 waves, each 64x64 = 4x4 MFMA tiles).
// PERM_OUT epilogue: stage C-tile in LDS (bf16, pad 136) -> 16B coalesced
// stores in attention layout. Non-perm (final) stage: direct fp32 stores.
// __launch_bounds__(256,4): cap VGPR at 128 so all 1024 blocks are
// co-resident (4 blocks/CU) -> no tail round.
// ---------------------------------------------------------------------
template <bool PERM_OUT, bool LRELU, bool OUT_F32>
__global__ __launch_bounds__(256, 4)
void mfma_clinear_kernel(const u16* __restrict__ Ar, const u16* __restrict__ Ai,
                         const u16* __restrict__ Wbt, const float* __restrict__ bias,
                         void* __restrict__ Yr_, void* __restrict__ Yi_)
{
    constexpr int SMEM_ELEMS = PERM_OUT ? (128 * 136) : (128 * 64);
    __shared__ __align__(16) u16 smem[SMEM_ELEMS];
    u16* sA = smem;                 // [128][32]
    u16* sB = smem + 128 * 32;      // [128][32]

    const int tid  = threadIdx.x;
    const int wave = tid >> 6;
    const int lane = tid & 63;
    const int m0   = blockIdx.x << 7;
    const int n0   = blockIdx.y << 7;
    const int mw   = (wave >> 1) << 6;   // 0 / 64
    const int nw   = (wave & 1) << 6;    // 0 / 64

    const int srow = tid >> 2;           // 0..63
    const int sk   = (tid & 3) << 3;     // 0,8,16,24
    const size_t arow0 = (size_t)(m0 + srow) * 512;
    const size_t arow1 = (size_t)(m0 + 64 + srow) * 512;
    const size_t brow0 = (size_t)(n0 + srow) * 1024;
    const size_t brow1 = (size_t)(n0 + 64 + srow) * 1024;

    u16* ldsA0 = sA + wave * 512;
    u16* ldsA1 = sA + 2048 + wave * 512;
    u16* ldsB0 = sB + wave * 512;
    u16* ldsB1 = sB + 2048 + wave * 512;

    f32x4 acc[4][4] = {};

    const int fr = lane & 15;            // fragment row (m or n)
    const int fq = (lane >> 4) << 3;     // fragment k offset

    for (int k0 = 0; k0 < 1024; k0 += 32) {
        const u16* As = (k0 < 512) ? Ar : Ai;
        const int  ak = (k0 & 511) + sk;
        __syncthreads();
        async16(ldsA0, As + arow0 + ak);
        async16(ldsA1, As + arow1 + ak);
        async16(ldsB0, Wbt + brow0 + k0 + sk);
        async16(ldsB1, Wbt + brow1 + k0 + sk);
        __syncthreads();

        bf16x8 af[4], bfr[4];
        #pragma unroll
        for (int i = 0; i < 4; ++i)
            af[i] = *(const bf16x8*)&sA[(mw + i * 16 + fr) * 32 + fq];
        #pragma unroll
        for (int j = 0; j < 4; ++j)
            bfr[j] = *(const bf16x8*)&sB[(nw + j * 16 + fr) * 32 + fq];

        #pragma unroll
        for (int i = 0; i < 4; ++i)
            #pragma unroll
            for (int j = 0; j < 4; ++j)
                acc[i][j] = __builtin_amdgcn_mfma_f32_16x16x32_bf16(af[i], bfr[j], acc[i][j], 0, 0, 0);
    }

    const int col_l = lane & 15;
    const int row_l = (lane >> 4) << 2;

    if constexpr (PERM_OUT) {
        // ---- stage C tile (bf16) in LDS, then coalesced 16B stores ----
        constexpr int LDN = 136;         // pad 128 -> 136 (conflict-light)
        __syncthreads();                 // main-loop LDS reads all done
        #pragma unroll
        for (int j = 0; j < 4; ++j) {
            const int ncl = nw + (j << 4) + col_l;      // 0..127 within tile
            const float bv = bias[n0 + ncl];
            #pragma unroll
            for (int i = 0; i < 4; ++i) {
                const int mrow = mw + (i << 4) + row_l;
                #pragma unroll
                for (int r = 0; r < 4; ++r) {
                    float v = acc[i][j][r] + bv;
                    if constexpr (LRELU) v = v >= 0.f ? v : 0.01f * v;
                    smem[(mrow + r) * LDN + ncl] = f2bf(v);
                }
            }
        }
        __syncthreads();
        u16* Yr = (u16*)Yr_;
        u16* Yi = (u16*)Yi_;
        #pragma unroll
        for (int s = 0; s < 8; ++s) {
            const int idx = (s << 8) + tid;     // 0..2047
            const int ml  = idx >> 4;           // 0..127
            const int c8  = (idx & 15) << 3;    // 0,8,..,120
            const uint4 dv = *(const uint4*)&smem[ml * LDN + c8];
            const int m    = m0 + ml;
            const int ncol = n0 + c8;
            const int part = ncol >> 9;
            const int nc   = ncol & 511;
            const int bb = m >> 12, cc = (m >> 9) & 7, tt = m & 511;
            const int hh = nc >> 6, dd = nc & 63;
            const size_t addr = ((size_t)(((bb << 3) + hh) * T_ + tt) << 9) + (cc << 6) + dd;
            u16* Y = part ? Yi : Yr;
            *(uint4*)(Y + addr) = dv;
        }
    } else {
        // ---- direct fp32 stores (64B segments per 16-lane group) ----
        #pragma unroll
        for (int j = 0; j < 4; ++j) {
            const int ncol = n0 + nw + (j << 4) + col_l;
            const float bv = bias[ncol];
            const int part = ncol >> 9;
            const int nc   = ncol & 511;
            float* Y = part ? (float*)Yi_ : (float*)Yr_;
            #pragma unroll
            for (int i = 0; i < 4; ++i) {
                const int mbase = m0 + mw + (i << 4) + row_l;
                #pragma unroll
                for (int r = 0; r < 4; ++r) {
                    float v = acc[i][j][r] + bv;
                    if constexpr (LRELU) v = v >= 0.f ? v : 0.01f * v;
                    Y[(size_t)(mbase + r) * 512 + nc] = v;
                }
            }
        }
    }
}

// ---------------------------------------------------------------------
// Attention: per (b,h,t) chunk w = (b*H+h)*T + t, matrices stored as
// 512 contiguous bf16 (c*64+d) at offset w*512.
// ---------------------------------------------------------------------
__global__ __launch_bounds__(256)
void attn_kernel(const u16* __restrict__ qr, const u16* __restrict__ qi,
                 const u16* __restrict__ kr, const u16* __restrict__ ki,
                 const u16* __restrict__ vr, const u16* __restrict__ vi,
                 u16* __restrict__ xr, u16* __restrict__ xi)
{
    constexpr int RS = 68;        // padded row stride (floats)
    constexpr int MS = 8 * RS;    // per matrix: 544 floats
    __shared__ float L[4][6 * MS];     // 52224 B
    __shared__ float S[4][128];        // sr(64) + si(64) per wave

    const int wave = threadIdx.x >> 6;
    const int lane = threadIdx.x & 63;
    const int w    = (blockIdx.x << 2) + wave;   // (b*H+h)*T + t
    const int cl   = lane >> 3;                  // c-index 0..7
    const int dl   = lane & 7;                   // 0..7
    const int d0   = dl << 3;                    // 0,8,..,56

    float* Lw = L[wave];
    const u16* srcs[6] = {qr, qi, kr, ki, vr, vi};
    const size_t gbase = ((size_t)w << 9) + (lane << 3);
    #pragma unroll
    for (int m2 = 0; m2 < 6; ++m2) {
        const uint4 u = *(const uint4*)(srcs[m2] + gbase);
        float* dst = Lw + m2 * MS + cl * RS + d0;
        dst[0]=bflo(u.x); dst[1]=bfhi(u.x);
        dst[2]=bflo(u.y); dst[3]=bfhi(u.y);
        dst[4]=bflo(u.z); dst[5]=bfhi(u.z);
        dst[6]=bflo(u.w); dst[7]=bfhi(u.w);
    }
    __syncthreads();

    { // scores: lane -> (c=cl, e=dl)
        const float* Qr = Lw + 0*MS + cl*RS;
        const float* Qi = Lw + 1*MS + cl*RS;
        const float* Kr = Lw + 2*MS + dl*RS;
        const float* Ki = Lw + 3*MS + dl*RS;
        float srr=0.f, sii=0.f, sri=0.f, sir=0.f;
        #pragma unroll 8
        for (int d = 0; d < 64; ++d) {
            srr = fmaf(Qr[d], Kr[d], srr);
            sii = fmaf(Qi[d], Ki[d], sii);
            sri = fmaf(Qr[d], Ki[d], sri);
            sir = fmaf(Qi[d], Kr[d], sir);
        }
        S[wave][lane]      = (srr + sii) * 0.125f;   // sr[c][e]
        S[wave][64 + lane] = (sri - sir) * 0.125f;   // si[c][e]
    }
    __syncthreads();

    const float* Vr = Lw + 4*MS;
    const float* Vi = Lw + 5*MS;
    const float* Sr = S[wave];
    const float* Si = S[wave] + 64;
    float outr[8] = {}, outi[8] = {};
    #pragma unroll
    for (int e = 0; e < 8; ++e) {
        const float sre = Sr[(cl<<3) + e];
        const float sie = Si[(cl<<3) + e];
        const float* vre = Vr + e*RS + d0;
        const float* vie = Vi + e*RS + d0;
        #pragma unroll
        for (int j = 0; j < 8; ++j) {
            outr[j] = fmaf(sre,  vre[j], outr[j]);
            outr[j] = fmaf(-sie, vie[j], outr[j]);
            outi[j] = fmaf(sie,  vre[j], outi[j]);
            outi[j] = fmaf(sre,  vie[j], outi[j]);
        }
    }

    // write merged (B,C,T,F) bf16 with lrelu
    const int tt = w & 511, hh = (w >> 9) & 7, bb = w >> 12;
    const size_t obase = ((size_t)(((bb << 3) + cl) * T_ + tt) << 9) + (hh << 6) + d0;
    u32 pr[4], pi[4];
    #pragma unroll
    for (int jj = 0; jj < 4; ++jj) {
        float r0 = outr[2*jj], r1 = outr[2*jj+1];
        float i0 = outi[2*jj], i1 = outi[2*jj+1];
        r0 = r0 >= 0.f ? r0 : 0.01f*r0;  r1 = r1 >= 0.f ? r1 : 0.01f*r1;
        i0 = i0 >= 0.f ? i0 : 0.01f*i0;  i1 = i1 >= 0.f ? i1 : 0.01f*i1;
        pr[jj] = (u32)f2bf(r0) | ((u32)f2bf(r1) << 16);
        pi[jj] = (u32)f2bf(i0) | ((u32)f2bf(i1) << 16);
    }
    *(uint4*)(xr + obase) = make_uint4(pr[0], pr[1], pr[2], pr[3]);
    *(uint4*)(xi + obase) = make_uint4(pi[0], pi[1], pi[2], pi[3]);
}

// ---------------------------------------------------------------------
extern "C" void kernel_launch(void* const* d_in, const int* in_sizes, int n_in,
                              void* d_out, int out_size, void* d_ws, size_t ws_size,
                              hipStream_t stream)
{
    (void)in_sizes; (void)n_in; (void)out_size; (void)ws_size;
    const float* act[6];
    for (int i = 0; i < 6; ++i) act[i] = (const float*)d_in[i];

    PrepArgs pa;
    for (int s = 0; s < 4; ++s) {
        pa.wr[s] = (const float*)d_in[6 + s*4 + 0];
        pa.br[s] = (const float*)d_in[6 + s*4 + 1];
        pa.wi[s] = (const float*)d_in[6 + s*4 + 2];
        pa.bi[s] = (const float*)d_in[6 + s*4 + 3];
    }

    const size_t SZ = (size_t)M_ * F_;        // 8,388,608 elements
    u16* ws = (u16*)d_ws;
    u16* a0 = ws + 0*SZ;  u16* a1 = ws + 1*SZ;   // query bf16 -> later k outputs
    u16* a2 = ws + 2*SZ;  u16* a3 = ws + 3*SZ;   // key bf16   -> later v outputs
    u16* a4 = ws + 4*SZ;  u16* a5 = ws + 5*SZ;   // value bf16 -> later attn outputs
    u16* q0 = ws + 6*SZ;  u16* q1 = ws + 7*SZ;   // q outputs
    u16*   wbig = ws + 8*SZ;                      // 4 x 1M bf16
    float* bbig = (float*)(wbig + 4u*1024*1024);  // 4 x 1024 fp32

    ConvArgs ca;
    ca.src[0]=act[0]; ca.src[1]=act[1]; ca.src[2]=act[2];
    ca.src[3]=act[3]; ca.src[4]=act[4]; ca.src[5]=act[5];
    ca.dst[0]=a0; ca.dst[1]=a1; ca.dst[2]=a2; ca.dst[3]=a3; ca.dst[4]=a4; ca.dst[5]=a5;

    convert6_kernel<<<dim3(1024, 6), 256, 0, stream>>>(ca);
    prep_weights_kernel<<<dim3(1024, 4), 256, 0, stream>>>(pa, wbig, bbig);

    dim3 ggrid(M_/128, 1024/128);
    // q stage
    mfma_clinear_kernel<true,  false, false><<<ggrid, 256, 0, stream>>>(
        a0, a1, wbig + 0u*1048576, bbig + 0*1024, q0, q1);
    // k stage (writes into a0/a1, already consumed)
    mfma_clinear_kernel<true,  false, false><<<ggrid, 256, 0, stream>>>(
        a2, a3, wbig + 1u*1048576, bbig + 1*1024, a0, a1);
    // v stage with leaky-relu (writes into a2/a3)
    mfma_clinear_kernel<true,  true,  false><<<ggrid, 256, 0, stream>>>(
        a4, a5, wbig + 2u*1048576, bbig + 2*1024, a2, a3);

    // attention: q=q0/q1, k=a0/a1, v=a2/a3 -> merged xr=a4, xi=a5
    attn_kernel<<<dim3((B_*H_*T_)/4), 256, 0, stream>>>(q0, q1, a0, a1, a2, a3, a4, a5);

    // output stage: fp32 out, no perm, no lrelu
    float* out_r = (float*)d_out;
    mfma_clinear_kernel<false, false, true><<<ggrid, 256, 0, stream>>>(
        a4, a5, wbig + 3u*1048576, bbig + 3*1024, out_r, out_r + SZ);
}

// Round 4
// 472.290 us; speedup vs baseline: 3.5609x; 1.0095x over previous
//
#include <hip/hip_runtime.h>

// Problem constants
#define B_  4
#define C_  8
#define T_  512
#define F_  512
#define H_  8
#define M_  (B_*C_*T_)   // 16384 rows

typedef unsigned short u16;
typedef unsigned int   u32;
typedef __bf16 bf16x8 __attribute__((ext_vector_type(8)));
typedef float  f32x4  __attribute__((ext_vector_type(4)));

// ---------- bf16 helpers ----------
__device__ __forceinline__ float bf2f(u16 s) {
    union { u32 u; float f; } c; c.u = ((u32)s) << 16; return c.f;
}
__device__ __forceinline__ u16 f2bf(float f) {
    union { float f; u32 u; } c; c.f = f;
    u32 r = c.u + 0x7fffu + ((c.u >> 16) & 1u);   // RNE
    return (u16)(r >> 16);
}
__device__ __forceinline__ float bflo(u32 v){ union{u32 u; float f;} c; c.u = v << 16;        return c.f; }
__device__ __forceinline__ float bfhi(u32 v){ union{u32 u; float f;} c; c.u = v & 0xffff0000u; return c.f; }

// async global->LDS, 16 B per lane. lds must be the wave-uniform base.
__device__ __forceinline__ void async16(u16* lds, const u16* g) {
    __builtin_amdgcn_global_load_lds(
        (const __attribute__((address_space(1))) u32*)g,
        (__attribute__((address_space(3))) u32*)lds,
        16, 0, 0);
}

// ---------------------------------------------------------------------
// K0: fp32 -> bf16 convert, 6 tensors. Coalesced: lane stride 16B,
// 4 float4/thread at +256 float4 strides. uint2 (8B) coalesced stores.
// ---------------------------------------------------------------------
struct ConvArgs { const float* src[6]; u16* dst[6]; };

__global__ __launch_bounds__(256)
void convert6_kernel(ConvArgs a)
{
    const int tid  = threadIdx.x;
    const int base = blockIdx.x * 1024 + tid;            // float4 index
    const float4* s = (const float4*)a.src[blockIdx.y];
    uint2*        d = (uint2*)a.dst[blockIdx.y];
    #pragma unroll
    for (int i = 0; i < 4; ++i) {
        const int idx = base + i * 256;
        const float4 v = s[idx];
        uint2 o;
        o.x = (u32)f2bf(v.x) | ((u32)f2bf(v.y) << 16);
        o.y = (u32)f2bf(v.z) | ((u32)f2bf(v.w) << 16);
        d[idx] = o;
    }
}

// ---------------------------------------------------------------------
// Kp: build WbigBT (1024x1024 bf16, [n][k]) and biasBig (1024 fp32) per stage.
// ---------------------------------------------------------------------
struct PrepArgs { const float* wr[4]; const float* wi[4]; const float* br[4]; const float* bi[4]; };

__global__ __launch_bounds__(256)
void prep_weights_kernel(PrepArgs a, u16* __restrict__ wbig, float* __restrict__ bbig)
{
    const int s   = blockIdx.y;
    const int idx = blockIdx.x * 256 + threadIdx.x;   // 0 .. 262143
    const int n   = idx >> 8;                         // 0..1023
    const int k0  = (idx & 255) << 2;                 // 0..1020
    const int nn = n & 511, kk = k0 & 511;
    const float* src; float sgn = 1.0f;
    if (n < 512) { if (k0 < 512) src = a.wr[s]; else { src = a.wi[s]; sgn = -1.0f; } }
    else         { if (k0 < 512) src = a.wi[s]; else   src = a.wr[s]; }
    const float4 v = *(const float4*)(src + (size_t)nn * 512 + kk);
    ushort4 q;
    q.x = f2bf(sgn * v.x); q.y = f2bf(sgn * v.y);
    q.z = f2bf(sgn * v.z); q.w = f2bf(sgn * v.w);
    *(ushort4*)(wbig + (size_t)s * 1048576 + (size_t)n * 1024 + k0) = q;

    if (blockIdx.x < 4) {
        const int bidx = blockIdx.x * 256 + threadIdx.x;   // 0..1023
        const float brv = a.br[s][bidx & 511];
        const float biv = a.bi[s][bidx & 511];
        bbig[s * 1024 + bidx] = (bidx < 512) ? (brv - biv) : (brv + biv);
    }
}

// ---------------------------------------------------------------------
// MFMA complex-linear as packed real GEMM:
//   Y[m,n] = sum_k Xcat[m,k] * WbigBT[n,k] + biasBig[n]
// Tile 128x128, BK=64 done as TWO BK=32 panels per barrier (halves the
// __syncthreads/vmcnt-drain count; keeps the proven 64B-row-stride LDS
// layout -> only free 2-way bank aliasing). 256 threads, 4 waves, each
// 64x64 = 4x4 MFMA tiles. LDS staging 32KB; PERM epilogue reuses smem
// (128x136 bf16 C-tile -> coalesced 16B stores in attention layout).
// __launch_bounds__(256,4): all 1024 blocks co-resident, no tail round.
// ---------------------------------------------------------------------
template <bool PERM_OUT, bool LRELU, bool OUT_F32>
__global__ __launch_bounds__(256, 4)
void mfma_clinear_kernel(const u16* __restrict__ Ar, const u16* __restrict__ Ai,
                         const u16* __restrict__ Wbt, const float* __restrict__ bias,
                         void* __restrict__ Yr_, void* __restrict__ Yi_)
{
    constexpr int SMEM_ELEMS = PERM_OUT ? (128 * 136) : (128 * 128);
    __shared__ __align__(16) u16 smem[SMEM_ELEMS];
    u16* sA = smem;               // 2 panels of [128][32]
    u16* sB = smem + 8192;        // 2 panels of [128][32]

    const int tid  = threadIdx.x;
    const int wave = tid >> 6;
    const int lane = tid & 63;
    const int m0   = blockIdx.x << 7;
    const int n0   = blockIdx.y << 7;
    const int mw   = (wave >> 1) << 6;   // 0 / 64
    const int nw   = (wave & 1) << 6;    // 0 / 64

    const int srow = tid >> 2;           // 0..63
    const int sk   = (tid & 3) << 3;     // 0,8,16,24
    const size_t arow0 = (size_t)(m0 + srow) * 512;
    const size_t arow1 = (size_t)(m0 + 64 + srow) * 512;
    const size_t brow0 = (size_t)(n0 + srow) * 1024;
    const size_t brow1 = (size_t)(n0 + 64 + srow) * 1024;

    u16* ldsA = sA + (wave << 9);
    u16* ldsB = sB + (wave << 9);

    f32x4 acc[4][4] = {};

    const int fr = lane & 15;            // fragment row (m or n)
    const int fq = (lane >> 4) << 3;     // fragment k offset

    for (int k0 = 0; k0 < 1024; k0 += 64) {
        const u16* As = (k0 < 512) ? Ar : Ai;
        const int  ak = (k0 & 511) + sk;
        __syncthreads();
        #pragma unroll
        for (int p = 0; p < 2; ++p) {
            const int kp = p << 5;
            async16(ldsA + p * 4096,        As + arow0 + ak + kp);
            async16(ldsA + p * 4096 + 2048, As + arow1 + ak + kp);
            async16(ldsB + p * 4096,        Wbt + brow0 + k0 + sk + kp);
            async16(ldsB + p * 4096 + 2048, Wbt + brow1 + k0 + sk + kp);
        }
        __syncthreads();

        #pragma unroll
        for (int p = 0; p < 2; ++p) {
            bf16x8 af[4], bfr[4];
            #pragma unroll
            for (int i = 0; i < 4; ++i)
                af[i] = *(const bf16x8*)&sA[p * 4096 + (mw + i * 16 + fr) * 32 + fq];
            #pragma unroll
            for (int j = 0; j < 4; ++j)
                bfr[j] = *(const bf16x8*)&sB[p * 4096 + (nw + j * 16 + fr) * 32 + fq];

            #pragma unroll
            for (int i = 0; i < 4; ++i)
                #pragma unroll
                for (int j = 0; j < 4; ++j)
                    acc[i][j] = __builtin_amdgcn_mfma_f32_16x16x32_bf16(af[i], bfr[j], acc[i][j], 0, 0, 0);
        }
    }

    const int col_l = lane & 15;
    const int row_l = (lane >> 4) << 2;

    if constexpr (PERM_OUT) {
        // ---- stage C tile (bf16) in LDS, then coalesced 16B stores ----
        constexpr int LDN = 136;         // pad 128 -> 136 (conflict-light)
        __syncthreads();                 // main-loop LDS reads all done
        #pragma unroll
        for (int j = 0; j < 4; ++j) {
            const int ncl = nw + (j << 4) + col_l;      // 0..127 within tile
            const float bv = bias[n0 + ncl];
            #pragma unroll
            for (int i = 0; i < 4; ++i) {
                const int mrow = mw + (i << 4) + row_l;
                #pragma unroll
                for (int r = 0; r < 4; ++r) {
                    float v = acc[i][j][r] + bv;
                    if constexpr (LRELU) v = v >= 0.f ? v : 0.01f * v;
                    smem[(mrow + r) * LDN + ncl] = f2bf(v);
                }
            }
        }
        __syncthreads();
        u16* Yr = (u16*)Yr_;
        u16* Yi = (u16*)Yi_;
        #pragma unroll
        for (int s = 0; s < 8; ++s) {
            const int idx = (s << 8) + tid;     // 0..2047
            const int ml  = idx >> 4;           // 0..127
            const int c8  = (idx & 15) << 3;    // 0,8,..,120
            const uint4 dv = *(const uint4*)&smem[ml * LDN + c8];
            const int m    = m0 + ml;
            const int ncol = n0 + c8;
            const int part = ncol >> 9;
            const int nc   = ncol & 511;
            const int bb = m >> 12, cc = (m >> 9) & 7, tt = m & 511;
            const int hh = nc >> 6, dd = nc & 63;
            const size_t addr = ((size_t)(((bb << 3) + hh) * T_ + tt) << 9) + (cc << 6) + dd;
            u16* Y = part ? Yi : Yr;
            *(uint4*)(Y + addr) = dv;
        }
    } else {
        // ---- direct fp32 stores (64B segments per 16-lane group) ----
        #pragma unroll
        for (int j = 0; j < 4; ++j) {
            const int ncol = n0 + nw + (j << 4) + col_l;
            const float bv = bias[ncol];
            const int part = ncol >> 9;
            const int nc   = ncol & 511;
            float* Y = part ? (float*)Yi_ : (float*)Yr_;
            #pragma unroll
            for (int i = 0; i < 4; ++i) {
                const int mbase = m0 + mw + (i << 4) + row_l;
                #pragma unroll
                for (int r = 0; r < 4; ++r) {
                    float v = acc[i][j][r] + bv;
                    if constexpr (LRELU) v = v >= 0.f ? v : 0.01f * v;
                    Y[(size_t)(mbase + r) * 512 + nc] = v;
                }
            }
        }
    }
}

// ---------------------------------------------------------------------
// Attention: per (b,h,t) chunk w = (b*H+h)*T + t, matrices stored as
// 512 contiguous bf16 (c*64+d) at offset w*512.
// ---------------------------------------------------------------------
__global__ __launch_bounds__(256)
void attn_kernel(const u16* __restrict__ qr, const u16* __restrict__ qi,
                 const u16* __restrict__ kr, const u16* __restrict__ ki,
                 const u16* __restrict__ vr, const u16* __restrict__ vi,
                 u16* __restrict__ xr, u16* __restrict__ xi)
{
    constexpr int RS = 68;        // padded row stride (floats)
    constexpr int MS = 8 * RS;    // per matrix: 544 floats
    __shared__ float L[4][6 * MS];     // 52224 B
    __shared__ float S[4][128];        // sr(64) + si(64) per wave

    const int wave = threadIdx.x >> 6;
    const int lane = threadIdx.x & 63;
    const int w    = (blockIdx.x << 2) + wave;   // (b*H+h)*T + t
    const int cl   = lane >> 3;                  // c-index 0..7
    const int dl   = lane & 7;                   // 0..7
    const int d0   = dl << 3;                    // 0,8,..,56

    float* Lw = L[wave];
    const u16* srcs[6] = {qr, qi, kr, ki, vr, vi};
    const size_t gbase = ((size_t)w << 9) + (lane << 3);
    #pragma unroll
    for (int m2 = 0; m2 < 6; ++m2) {
        const uint4 u = *(const uint4*)(srcs[m2] + gbase);
        float* dst = Lw + m2 * MS + cl * RS + d0;
        dst[0]=bflo(u.x); dst[1]=bfhi(u.x);
        dst[2]=bflo(u.y); dst[3]=bfhi(u.y);
        dst[4]=bflo(u.z); dst[5]=bfhi(u.z);
        dst[6]=bflo(u.w); dst[7]=bfhi(u.w);
    }
    __syncthreads();

    { // scores: lane -> (c=cl, e=dl)
        const float* Qr = Lw + 0*MS + cl*RS;
        const float* Qi = Lw + 1*MS + cl*RS;
        const float* Kr = Lw + 2*MS + dl*RS;
        const float* Ki = Lw + 3*MS + dl*RS;
        float srr=0.f, sii=0.f, sri=0.f, sir=0.f;
        #pragma unroll 8
        for (int d = 0; d < 64; ++d) {
            srr = fmaf(Qr[d], Kr[d], srr);
            sii = fmaf(Qi[d], Ki[d], sii);
            sri = fmaf(Qr[d], Ki[d], sri);
            sir = fmaf(Qi[d], Kr[d], sir);
        }
        S[wave][lane]      = (srr + sii) * 0.125f;   // sr[c][e]
        S[wave][64 + lane] = (sri - sir) * 0.125f;   // si[c][e]
    }
    __syncthreads();

    const float* Vr = Lw + 4*MS;
    const float* Vi = Lw + 5*MS;
    const float* Sr = S[wave];
    const float* Si = S[wave] + 64;
    float outr[8] = {}, outi[8] = {};
    #pragma unroll
    for (int e = 0; e < 8; ++e) {
        const float sre = Sr[(cl<<3) + e];
        const float sie = Si[(cl<<3) + e];
        const float* vre = Vr + e*RS + d0;
        const float* vie = Vi + e*RS + d0;
        #pragma unroll
        for (int j = 0; j < 8; ++j) {
            outr[j] = fmaf(sre,  vre[j], outr[j]);
            outr[j] = fmaf(-sie, vie[j], outr[j]);
            outi[j] = fmaf(sie,  vre[j], outi[j]);
            outi[j] = fmaf(sre,  vie[j], outi[j]);
        }
    }

    // write merged (B,C,T,F) bf16 with lrelu
    const int tt = w & 511, hh = (w >> 9) & 7, bb = w >> 12;
    const size_t obase = ((size_t)(((bb << 3) + cl) * T_ + tt) << 9) + (hh << 6) + d0;
    u32 pr[4], pi[4];
    #pragma unroll
    for (int jj = 0; jj < 4; ++jj) {
        float r0 = outr[2*jj], r1 = outr[2*jj+1];
        float i0 = outi[2*jj], i1 = outi[2*jj+1];
        r0 = r0 >= 0.f ? r0 : 0.01f*r0;  r1 = r1 >= 0.f ? r1 : 0.01f*r1;
        i0 = i0 >= 0.f ? i0 : 0.01f*i0;  i1 = i1 >= 0.f ? i1 : 0.01f*i1;
        pr[jj] = (u32)f2bf(r0) | ((u32)f2bf(r1) << 16);
        pi[jj] = (u32)f2bf(i0) | ((u32)f2bf(i1) << 16);
    }
    *(uint4*)(xr + obase) = make_uint4(pr[0], pr[1], pr[2], pr[3]);
    *(uint4*)(xi + obase) = make_uint4(pi[0], pi[1], pi[2], pi[3]);
}

// ---------------------------------------------------------------------
extern "C" void kernel_launch(void* const* d_in, const int* in_sizes, int n_in,
                              void* d_out, int out_size, void* d_ws, size_t ws_size,
                              hipStream_t stream)
{
    (void)in_sizes; (void)n_in; (void)out_size; (void)ws_size;
    const float* act[6];
    for (int i = 0; i < 6; ++i) act[i] = (const float*)d_in[i];

    PrepArgs pa;
    for (int s = 0; s < 4; ++s) {
        pa.wr[s] = (const float*)d_in[6 + s*4 + 0];
        pa.br[s] = (const float*)d_in[6 + s*4 + 1];
        pa.wi[s] = (const float*)d_in[6 + s*4 + 2];
        pa.bi[s] = (const float*)d_in[6 + s*4 + 3];
    }

    const size_t SZ = (size_t)M_ * F_;        // 8,388,608 elements
    u16* ws = (u16*)d_ws;
    u16* a0 = ws + 0*SZ;  u16* a1 = ws + 1*SZ;   // query bf16 -> later k outputs
    u16* a2 = ws + 2*SZ;  u16* a3 = ws + 3*SZ;   // key bf16   -> later v outputs
    u16* a4 = ws + 4*SZ;  u16* a5 = ws + 5*SZ;   // value bf16 -> later attn outputs
    u16* q0 = ws + 6*SZ;  u16* q1 = ws + 7*SZ;   // q outputs
    u16*   wbig = ws + 8*SZ;                      // 4 x 1M bf16
    float* bbig = (float*)(wbig + 4u*1024*1024);  // 4 x 1024 fp32

    ConvArgs ca;
    ca.src[0]=act[0]; ca.src[1]=act[1]; ca.src[2]=act[2];
    ca.src[3]=act[3]; ca.src[4]=act[4]; ca.src[5]=act[5];
    ca.dst[0]=a0; ca.dst[1]=a1; ca.dst[2]=a2; ca.dst[3]=a3; ca.dst[4]=a4; ca.dst[5]=a5;

    convert6_kernel<<<dim3(2048, 6), 256, 0, stream>>>(ca);
    prep_weights_kernel<<<dim3(1024, 4), 256, 0, stream>>>(pa, wbig, bbig);

    dim3 ggrid(M_/128, 1024/128);
    // q stage
    mfma_clinear_kernel<true,  false, false><<<ggrid, 256, 0, stream>>>(
        a0, a1, wbig + 0u*1048576, bbig + 0*1024, q0, q1);
    // k stage (writes into a0/a1, already consumed)
    mfma_clinear_kernel<true,  false, false><<<ggrid, 256, 0, stream>>>(
        a2, a3, wbig + 1u*1048576, bbig + 1*1024, a0, a1);
    // v stage with leaky-relu (writes into a2/a3)
    mfma_clinear_kernel<true,  true,  false><<<ggrid, 256, 0, stream>>>(
        a4, a5, wbig + 2u*1048576, bbig + 2*1024, a2, a3);

    // attention: q=q0/q1, k=a0/a1, v=a2/a3 -> merged xr=a4, xi=a5
    attn_kernel<<<dim3((B_*H_*T_)/4), 256, 0, stream>>>(q0, q1, a0, a1, a2, a3, a4, a5);

    // output stage: fp32 out, no perm, no lrelu
    float* out_r = (float*)d_out;
    mfma_clinear_kernel<false, false, true><<<ggrid, 256, 0, stream>>>(
        a4, a5, wbig + 3u*1048576, bbig + 3*1024, out_r, out_r + SZ);
}